// Round 7
// baseline (655.350 us; speedup 1.0000x reference)
//
#include <hip/hip_runtime.h>

#define E_DIM 1024
#define NH 16
#define DH 64
#define BSEG 8
#define LQ 512
#define LKV 1024

typedef short bf16x8 __attribute__((ext_vector_type(8)));
typedef float f32x4 __attribute__((ext_vector_type(4)));
typedef unsigned short u16;

// round-to-nearest-even fp32 -> bf16 bits
__device__ __forceinline__ u16 f2bf(float x) {
    unsigned u = __float_as_uint(x);
    u += 0x7FFF + ((u >> 16) & 1);
    return (u16)(u >> 16);
}

// async global->LDS, 16B per lane; lds dest wave-uniform base + lane*16
__device__ __forceinline__ void async16(const void* g, const void* l) {
    __builtin_amdgcn_global_load_lds(
        (const __attribute__((address_space(1))) unsigned int*)g,
        (__attribute__((address_space(3))) unsigned int*)l, 16, 0, 0);
}

// packed RNE f32->bf16 pair -> one u32 (v_cvt_pk_bf16_f32)
__device__ __forceinline__ unsigned pk2(float a, float b) {
    unsigned r;
    asm("v_cvt_pk_bf16_f32 %0, %1, %2" : "=v"(r) : "v"(a), "v"(b));
    return r;
}

// ---------------------------------------------------------------------------
// Fused fp32->bf16 convert for all 4 inputs (one launch).  (verbatim)
// ---------------------------------------------------------------------------
__global__ __launch_bounds__(256) void cvt_all_kernel(
    const float* __restrict__ inputs, const float* __restrict__ queries,
    const float* __restrict__ w_in, const float* __restrict__ w_out,
    u16* __restrict__ ib, u16* __restrict__ qb,
    u16* __restrict__ wib, u16* __restrict__ wob)
{
    int blk = blockIdx.x;
    const float* s; u16* d; int base;
    if (blk < 8192)        { s = inputs;  d = ib;  base = blk; }
    else if (blk < 12288)  { s = queries; d = qb;  base = blk - 8192; }
    else if (blk < 15360)  { s = w_in;    d = wib; base = blk - 12288; }
    else                   { s = w_out;   d = wob; base = blk - 15360; }
    int i = base * 256 + threadIdx.x;
    float4 v = ((const float4*)s)[i];
    ushort4 o;
    o.x = f2bf(v.x); o.y = f2bf(v.y); o.z = f2bf(v.z); o.w = f2bf(v.w);
    ((ushort4*)d)[i] = o;
}

// ---------------------------------------------------------------------------
// Fused Q/K/V projection GEMM.  BK=64 two-half staging, launch_bounds(256,5)
// (round-4 skeleton, proven 60 µs) + swapped MFMA operands for K/Q blocks
// (round-1/3-proven epilogue: acc regs hold 4 consecutive d per token ->
// contiguous ushort4 frag16 stores; 4x fewer, 4x wider epilogue stores).
// V blocks keep original operand order + sigma' epilogue.  VGPR headroom:
// main loop is 48 regs, cap ~102, so the swap no longer costs occupancy.
// ---------------------------------------------------------------------------
__global__ __launch_bounds__(256, 5) void proj_gemm_kernel(
    const u16* __restrict__ inputs_b, const u16* __restrict__ queries_b,
    const u16* __restrict__ w_in_b, const float* __restrict__ b_in,
    u16* __restrict__ Kf, u16* __restrict__ Qf, u16* __restrict__ Vf)
{
    __shared__ u16 As[2][128 * 32];
    __shared__ u16 Ws[2][128 * 32];

    const int bid = blockIdx.x;
    const bool isQ = (bid >= 1024);
    const int x = bid & 7;
    int bx, by;
    if (!isQ) { int i = bid >> 3;          bx = i >> 3; by = x * 8 + (i & 7); }
    else      { int i = (bid - 1024) >> 3; bx = i >> 2; by = x * 4 + (i & 3); }

    const bool isV = (!isQ) && (bx >= 8);

    const u16* A = isQ ? queries_b : inputs_b;
    const u16* W = w_in_b + (isQ ? 0 : (size_t)E_DIM * E_DIM);
    const float* bias = b_in + (isQ ? 0 : E_DIM);
    const int m_blk = by * 128;
    const int n_blk = bx * 128;
    const int K = E_DIM;

    const int tid = threadIdx.x;
    const int l = tid & 63;
    const int w = tid >> 6;
    const int m0 = (w & 1) * 64;
    const int n0 = (w >> 1) * 64;
    const int quad = l >> 4;
    const int c = l & 15;

    f32x4 acc[4][4];
    #pragma unroll
    for (int i = 0; i < 4; ++i)
        #pragma unroll
        for (int j = 0; j < 4; ++j)
            acc[i][j] = (f32x4){0.f, 0.f, 0.f, 0.f};

    const int srow = l >> 2;            // 0..15
    const int skoff = (l & 3) * 8;      // u16 col within a 32-col half
    const u16* Ag = A + (size_t)(m_blk + w * 32 + srow) * K + skoff;
    const u16* Wg = W + (size_t)(n_blk + w * 32 + srow) * K + skoff;

    for (int k0 = 0; k0 < K; k0 += 64) {
        __syncthreads();
        #pragma unroll
        for (int hf = 0; hf < 2; ++hf)
            #pragma unroll
            for (int t = 0; t < 2; ++t) {
                const size_t soff = (size_t)t * 16 * K + k0 + hf * 32;
                const size_t doff = (size_t)(w * 32 + t * 16) * 32;
                async16(Ag + soff, &As[hf][0] + doff);
                async16(Wg + soff, &Ws[hf][0] + doff);
            }
        __syncthreads();

        #pragma unroll
        for (int hf = 0; hf < 2; ++hf) {
            bf16x8 af[4], wf[4];
            #pragma unroll
            for (int t = 0; t < 4; ++t) {
                af[t] = *(const bf16x8*)&As[hf][(m0 + t * 16 + c) * 32 + quad * 8];
                wf[t] = *(const bf16x8*)&Ws[hf][(n0 + t * 16 + c) * 32 + quad * 8];
            }
            if (isV) {
                #pragma unroll
                for (int i = 0; i < 4; ++i)
                    #pragma unroll
                    for (int j = 0; j < 4; ++j)
                        acc[i][j] = __builtin_amdgcn_mfma_f32_16x16x32_bf16(
                            af[i], wf[j], acc[i][j], 0, 0, 0);
            } else {
                // swapped operands: D rows = W-cols (d), D cols = tokens
                #pragma unroll
                for (int i = 0; i < 4; ++i)
                    #pragma unroll
                    for (int j = 0; j < 4; ++j)
                        acc[i][j] = __builtin_amdgcn_mfma_f32_16x16x32_bf16(
                            wf[j], af[i], acc[i][j], 0, 0, 0);
            }
        }
    }

    if (!isV) {
        // K/Q epilogue, swapped layout (round-1/3 proven): lane holds
        // d = colb..colb+3 for token m_blk+m0+i*16+c -> ushort4 in frag16.
        u16* dst = isQ ? Qf : Kf;
        #pragma unroll
        for (int jj = 0; jj < 4; ++jj) {
            const int colb = n_blk + n0 + jj * 16 + quad * 4;
            const float4 bv = *(const float4*)&bias[colb];
            const int hh = colb >> 6;
            const int d  = colb & 63;
            const size_t doff = (size_t)(d >> 3) * 128 + (size_t)c * 8 + (d & 7);
            #pragma unroll
            for (int i = 0; i < 4; ++i) {
                const int t16 = ((m_blk + m0) >> 4) + i;
                ushort4 pk;
                pk.x = f2bf(acc[i][jj][0] + bv.x);
                pk.y = f2bf(acc[i][jj][1] + bv.y);
                pk.z = f2bf(acc[i][jj][2] + bv.z);
                pk.w = f2bf(acc[i][jj][3] + bv.w);
                *(ushort4*)(dst + ((size_t)(t16 * NH + hh)) * 1024 + doff) = pk;
            }
        }
    } else {
        // V epilogue: sigma'-frag pack (verbatim)
        #pragma unroll
        for (int jj = 0; jj < 4; ++jj) {
            int col = n_blk + n0 + jj * 16 + c;
            float bv = bias[col];
            int vcol = col - 1024;
            int hv = vcol >> 6, d = vcol & 63;
            int td = d >> 4, ct = d & 15;
            #pragma unroll
            for (int i = 0; i < 4; ++i) {
                int tok = m_blk + m0 + i * 16;
                int g32 = tok >> 5;
                int jo = (tok & 16) >> 2;          // 0 or 4
                ushort4 pk;
                pk.x = f2bf(acc[i][jj][0] + bv);
                pk.y = f2bf(acc[i][jj][1] + bv);
                pk.z = f2bf(acc[i][jj][2] + bv);
                pk.w = f2bf(acc[i][jj][3] + bv);
                *(ushort4*)(Vf + ((size_t)(g32 * NH + hv)) * 2048
                            + (size_t)((td * 4 + quad) * 16 + ct) * 8 + jo) = pk;
            }
        }
    }
}

// ---------------------------------------------------------------------------
// Attention.  (verbatim round-6: split pipeline qk(t+1) before smpv(t),
// defer-max, deferred l-reduction, cvt_pk pack, setprio around MFMA)
// ---------------------------------------------------------------------------
struct Kfrags { bf16x8 kf[4][2]; };
struct Vfrags { bf16x8 vf[2][4]; };

__global__ __launch_bounds__(256) void attn_kernel(
    const u16* __restrict__ Qf, const u16* __restrict__ Kf,
    const u16* __restrict__ Vf, u16* __restrict__ Ob)
{
    const int tid = threadIdx.x;
    const int l = tid & 63;
    const int w = tid >> 6;
    const int quad = l >> 4;
    const int c = l & 15;
    const int bid = blockIdx.x;
    const int h = bid & 15;
    const int b = (bid >> 4) & 7;
    const int qt = bid >> 7;
    const int q0 = b * LQ + qt * 64 + w * 16;
    const float C1 = 0.18033688011112042f;   // (1/8)*log2(e)
    const float THR = 8.0f;                  // defer-max threshold

    bf16x8 qf[2];
    {
        size_t qb = ((size_t)((q0 >> 4) * NH + h)) * 1024 + (size_t)l * 8;
        qf[0] = *(const bf16x8*)(Qf + qb);
        qf[1] = *(const bf16x8*)(Qf + qb + 512);
    }

    f32x4 o[4];
    #pragma unroll
    for (int td = 0; td < 4; ++td) o[td] = (f32x4){0.f, 0.f, 0.f, 0.f};
    float m_i = -1e30f;
    float lpart = 0.f;

    auto load_k = [&](int kv0, Kfrags& dst) {
        const int kvg = b * LKV + kv0;
        #pragma unroll
        for (int nt = 0; nt < 4; ++nt) {
            size_t kb = ((size_t)((((kvg >> 4) + nt) * NH) + h)) * 1024 + (size_t)l * 8;
            dst.kf[nt][0] = *(const bf16x8*)(Kf + kb);
            dst.kf[nt][1] = *(const bf16x8*)(Kf + kb + 512);
        }
    };
    auto load_v = [&](int kv0, Vfrags& dst) {
        const int kvg = b * LKV + kv0;
        #pragma unroll
        for (int g = 0; g < 2; ++g) {
            size_t vb = ((size_t)((((kvg >> 5) + g) * NH) + h)) * 2048 + (size_t)l * 8;
            #pragma unroll
            for (int td = 0; td < 4; ++td)
                dst.vf[g][td] = *(const bf16x8*)(Vf + vb + td * 512);
        }
    };

    auto qk = [&](Kfrags& ck, f32x4* s) {
        #pragma unroll
        for (int nt = 0; nt < 4; ++nt) s[nt] = (f32x4){0.f, 0.f, 0.f, 0.f};
        __builtin_amdgcn_s_setprio(1);
        #pragma unroll
        for (int nt = 0; nt < 4; ++nt)
            #pragma unroll
            for (int hk = 0; hk < 2; ++hk)
                s[nt] = __builtin_amdgcn_mfma_f32_16x16x32_bf16(
                    ck.kf[nt][hk], qf[hk], s[nt], 0, 0, 0);
        __builtin_amdgcn_s_setprio(0);
    };

    auto smpv = [&](f32x4* s, Vfrags& cv) {
        float m01 = fmaxf(fmaxf(s[0][0], s[0][1]), fmaxf(s[0][2], s[0][3]));
        float m23 = fmaxf(fmaxf(s[1][0], s[1][1]), fmaxf(s[1][2], s[1][3]));
        float m45 = fmaxf(fmaxf(s[2][0], s[2][1]), fmaxf(s[2][2], s[2][3]));
        float m67 = fmaxf(fmaxf(s[3][0], s[3][1]), fmaxf(s[3][2], s[3][3]));
        float vml = fmaxf(fmaxf(m01, m23), fmaxf(m45, m67));

        if (!__all(vml - m_i <= THR)) {
            float vmr = vml;
            vmr = fmaxf(vmr, __shfl_xor(vmr, 16, 64));
            vmr = fmaxf(vmr, __shfl_xor(vmr, 32, 64));
            float mnew = fmaxf(m_i, vmr);
            float alpha = __builtin_amdgcn_exp2f((m_i - mnew) * C1);
            m_i = mnew;
            lpart *= alpha;
            float ar[4];
            #pragma unroll
            for (int r = 0; r < 4; ++r) ar[r] = __shfl(alpha, quad * 4 + r, 16);
            #pragma unroll
            for (int td = 0; td < 4; ++td)
                #pragma unroll
                for (int r = 0; r < 4; ++r) o[td][r] *= ar[r];
        }

        float p[4][4];
        float rs = 0.f;
        #pragma unroll
        for (int nt = 0; nt < 4; ++nt)
            #pragma unroll
            for (int r = 0; r < 4; ++r) {
                p[nt][r] = __builtin_amdgcn_exp2f((s[nt][r] - m_i) * C1);
                rs += p[nt][r];
            }
        lpart += rs;

        bf16x8 af[2];
        #pragma unroll
        for (int g = 0; g < 2; ++g) {
            union { unsigned u[4]; bf16x8 v; } r_;
            r_.u[0] = pk2(p[2 * g][0],     p[2 * g][1]);
            r_.u[1] = pk2(p[2 * g][2],     p[2 * g][3]);
            r_.u[2] = pk2(p[2 * g + 1][0], p[2 * g + 1][1]);
            r_.u[3] = pk2(p[2 * g + 1][2], p[2 * g + 1][3]);
            af[g] = r_.v;
        }

        __builtin_amdgcn_s_setprio(1);
        #pragma unroll
        for (int g = 0; g < 2; ++g)
            #pragma unroll
            for (int td = 0; td < 4; ++td)
                o[td] = __builtin_amdgcn_mfma_f32_16x16x32_bf16(
                    af[g], cv.vf[g][td], o[td], 0, 0, 0);
        __builtin_amdgcn_s_setprio(0);
    };

    Kfrags K0, K1;
    Vfrags V0, V1;
    f32x4 s0[4], s1[4];
    load_k(0, K0);
    load_v(0, V0);
    load_k(64, K1);
    qk(K0, s0);
    #pragma unroll
    for (int it = 0; it < 16; it += 2) {
        if (it + 2 < 16) load_k((it + 2) * 64, K0);
        load_v((it + 1) * 64, V1);
        qk(K1, s1);
        smpv(s0, V0);
        if (it + 3 < 16) load_k((it + 3) * 64, K1);
        if (it + 2 < 16) { load_v((it + 2) * 64, V0); qk(K0, s0); }
        smpv(s1, V1);
    }

    float l_i = lpart;
    l_i += __shfl_xor(l_i, 16, 64);
    l_i += __shfl_xor(l_i, 32, 64);
    float invl = 1.f / l_i;
    float ir[4];
    #pragma unroll
    for (int r = 0; r < 4; ++r) ir[r] = __shfl(invl, quad * 4 + r, 16);
    #pragma unroll
    for (int td = 0; td < 4; ++td)
        #pragma unroll
        for (int r = 0; r < 4; ++r)
            Ob[(size_t)(q0 + quad * 4 + r) * E_DIM + h * 64 + td * 16 + c] =
                f2bf(o[td][r] * ir[r]);
}

// ---------------------------------------------------------------------------
// Output projection: out[4096,1024] = Ob @ w_out^T + b_out (fp32 out).
// Round-7 retile: 64x64 tiles, grid 1024 (4 blocks/CU, 16 waves/CU vs the
// old 128x128/256-grid's 1 wave/SIMD).  Same proven 32-col-half staging,
// same swapped-operand epilogue with float4 stores.  2x2 warps of 32x32.
// ---------------------------------------------------------------------------
__global__ __launch_bounds__(256) void out_gemm_kernel(
    const u16* __restrict__ A, const u16* __restrict__ W,
    const float* __restrict__ bias, float* __restrict__ Cf)
{
    __shared__ u16 As[2][64 * 32];
    __shared__ u16 Ws[2][64 * 32];

    const int K = E_DIM, N = E_DIM;
    const int bid = blockIdx.x;
    const int x = bid & 7;
    const int i_ = bid >> 3;            // 0..127
    const int m_blk = (x * 8 + (i_ & 7)) * 64;   // 64 m-blocks
    const int n_blk = (i_ >> 3) * 64;            // 16 n-blocks

    const int tid = threadIdx.x;
    const int l = tid & 63;
    const int w = tid >> 6;
    const int m0 = (w & 1) * 32;
    const int n0 = (w >> 1) * 32;
    const int quad = l >> 4;
    const int c = l & 15;

    f32x4 acc[2][2];
    #pragma unroll
    for (int i = 0; i < 2; ++i)
        #pragma unroll
        for (int j = 0; j < 2; ++j)
            acc[i][j] = (f32x4){0.f, 0.f, 0.f, 0.f};

    const int srow = l >> 2;            // 0..15
    const int skoff = (l & 3) * 8;
    const u16* Ag = A + (size_t)(m_blk + w * 16 + srow) * K + skoff;
    const u16* Wg = W + (size_t)(n_blk + w * 16 + srow) * K + skoff;

    for (int k0 = 0; k0 < K; k0 += 64) {
        __syncthreads();
        #pragma unroll
        for (int hf = 0; hf < 2; ++hf) {
            const size_t soff = (size_t)(k0 + hf * 32);
            const size_t doff = (size_t)(w * 16) * 32;
            async16(Ag + soff, &As[hf][0] + doff);
            async16(Wg + soff, &Ws[hf][0] + doff);
        }
        __syncthreads();

        #pragma unroll
        for (int hf = 0; hf < 2; ++hf) {
            bf16x8 af[2], wf[2];
            #pragma unroll
            for (int t = 0; t < 2; ++t) {
                af[t] = *(const bf16x8*)&As[hf][(m0 + t * 16 + c) * 32 + quad * 8];
                wf[t] = *(const bf16x8*)&Ws[hf][(n0 + t * 16 + c) * 32 + quad * 8];
            }
            #pragma unroll
            for (int i = 0; i < 2; ++i)
                #pragma unroll
                for (int j = 0; j < 2; ++j)
                    acc[i][j] = __builtin_amdgcn_mfma_f32_16x16x32_bf16(
                        wf[j], af[i], acc[i][j], 0, 0, 0);
        }
    }

    #pragma unroll
    for (int j = 0; j < 2; ++j) {
        const int colb = n_blk + n0 + j * 16 + quad * 4;
        const float4 bv = *(const float4*)&bias[colb];
        #pragma unroll
        for (int i = 0; i < 2; ++i) {
            const int row = m_blk + m0 + i * 16 + c;
            float4 o4;
            o4.x = acc[i][j][0] + bv.x;
            o4.y = acc[i][j][1] + bv.y;
            o4.z = acc[i][j][2] + bv.z;
            o4.w = acc[i][j][3] + bv.w;
            *(float4*)&Cf[(size_t)row * N + colb] = o4;
        }
    }
}

// ---------------------------------------------------------------------------
extern "C" void kernel_launch(void* const* d_in, const int* in_sizes, int n_in,
                              void* d_out, int out_size, void* d_ws, size_t ws_size,
                              hipStream_t stream) {
    const float* inputs  = (const float*)d_in[0];   // [8192,1024]
    const float* queries = (const float*)d_in[1];   // [4096,1024]
    const float* w_in    = (const float*)d_in[2];   // [3072,1024]
    const float* b_in    = (const float*)d_in[3];   // [3072]
    const float* w_out   = (const float*)d_in[4];   // [1024,1024]
    const float* b_out   = (const float*)d_in[5];   // [1024]
    float* out = (float*)d_out;                     // [4096,1024] fp32

    const int NQ = BSEG * LQ;    // 4096
    const int NKV = BSEG * LKV;  // 8192

    // workspace: 80 MB
    u16* inputs_b  = (u16*)d_ws;                                   // 16 MB
    u16* queries_b = inputs_b  + (size_t)NKV * E_DIM;              //  8 MB
    u16* w_in_b    = queries_b + (size_t)NQ * E_DIM;               //  6 MB
    u16* w_out_b   = w_in_b    + (size_t)3 * E_DIM * E_DIM;        //  2 MB
    u16* Qf        = w_out_b   + (size_t)E_DIM * E_DIM;            //  8 MB
    u16* Kf        = Qf        + (size_t)NQ * E_DIM;               // 16 MB
    u16* Vf        = Kf        + (size_t)NKV * E_DIM;              // 16 MB
    u16* Ob        = Vf        + (size_t)NKV * E_DIM;              //  8 MB

    dim3 blk(256);

    cvt_all_kernel<<<16384, blk, 0, stream>>>(
        inputs, queries, w_in, w_out, inputs_b, queries_b, w_in_b, w_out_b);

    proj_gemm_kernel<<<1280, blk, 0, stream>>>(
        inputs_b, queries_b, w_in_b, b_in, Kf, Qf, Vf);

    attn_kernel<<<1024, blk, 0, stream>>>(Qf, Kf, Vf, Ob);

    out_gemm_kernel<<<1024, blk, 0, stream>>>(
        Ob, w_out_b, b_out, out);
}

// Round 8
// 223.269 us; speedup vs baseline: 2.9352x; 2.9352x over previous
//
#include <hip/hip_runtime.h>

#define E_DIM 1024
#define NH 16
#define DH 64
#define BSEG 8
#define LQ 512
#define LKV 1024

typedef short bf16x8 __attribute__((ext_vector_type(8)));
typedef float f32x4 __attribute__((ext_vector_type(4)));
typedef unsigned short u16;

// round-to-nearest-even fp32 -> bf16 bits
__device__ __forceinline__ u16 f2bf(float x) {
    unsigned u = __float_as_uint(x);
    u += 0x7FFF + ((u >> 16) & 1);
    return (u16)(u >> 16);
}

// async global->LDS, 16B per lane; lds dest wave-uniform base + lane*16
__device__ __forceinline__ void async16(const void* g, const void* l) {
    __builtin_amdgcn_global_load_lds(
        (const __attribute__((address_space(1))) unsigned int*)g,
        (__attribute__((address_space(3))) unsigned int*)l, 16, 0, 0);
}

// packed RNE f32->bf16 pair -> one u32 (v_cvt_pk_bf16_f32)
__device__ __forceinline__ unsigned pk2(float a, float b) {
    unsigned r;
    asm("v_cvt_pk_bf16_f32 %0, %1, %2" : "=v"(r) : "v"(a), "v"(b));
    return r;
}

// ---------------------------------------------------------------------------
// Fused fp32->bf16 convert for all 4 inputs (one launch).  (verbatim)
// ---------------------------------------------------------------------------
__global__ __launch_bounds__(256) void cvt_all_kernel(
    const float* __restrict__ inputs, const float* __restrict__ queries,
    const float* __restrict__ w_in, const float* __restrict__ w_out,
    u16* __restrict__ ib, u16* __restrict__ qb,
    u16* __restrict__ wib, u16* __restrict__ wob)
{
    int blk = blockIdx.x;
    const float* s; u16* d; int base;
    if (blk < 8192)        { s = inputs;  d = ib;  base = blk; }
    else if (blk < 12288)  { s = queries; d = qb;  base = blk - 8192; }
    else if (blk < 15360)  { s = w_in;    d = wib; base = blk - 12288; }
    else                   { s = w_out;   d = wob; base = blk - 15360; }
    int i = base * 256 + threadIdx.x;
    float4 v = ((const float4*)s)[i];
    ushort4 o;
    o.x = f2bf(v.x); o.y = f2bf(v.y); o.z = f2bf(v.z); o.w = f2bf(v.w);
    ((ushort4*)d)[i] = o;
}

// ---------------------------------------------------------------------------
// Fused Q/K/V projection GEMM.  VERBATIM round-6 (proven 60.1-61.6 µs,
// VGPR 48, AGPR-resident accumulators, no spill):
//  - BK=64 two-half staging, single LDS buffer pair, 2 barriers/K-step
//  - UNIFORM MFMA operand order (af,wf) for ALL blocks
//  - scatter frag16 epilogue for K/Q, sigma' epilogue for V
//  - __launch_bounds__(256,5): 5 blocks/CU co-resident (160 KB LDS exactly)
// NOTE (round-7 lesson): do NOT reintroduce the swapped-operand epilogue
// here — it needs ~132 VGPR and under the (256,5) cap the compiler spills
// accumulators to scratch (WRITE_SIZE ballooned 43.5 MB -> 1.65 GB, 8x).
// ---------------------------------------------------------------------------
__global__ __launch_bounds__(256, 5) void proj_gemm_kernel(
    const u16* __restrict__ inputs_b, const u16* __restrict__ queries_b,
    const u16* __restrict__ w_in_b, const float* __restrict__ b_in,
    u16* __restrict__ Kf, u16* __restrict__ Qf, u16* __restrict__ Vf)
{
    __shared__ u16 As[2][128 * 32];
    __shared__ u16 Ws[2][128 * 32];

    const int bid = blockIdx.x;
    const bool isQ = (bid >= 1024);
    const int x = bid & 7;
    int bx, by;
    if (!isQ) { int i = bid >> 3;          bx = i >> 3; by = x * 8 + (i & 7); }
    else      { int i = (bid - 1024) >> 3; bx = i >> 2; by = x * 4 + (i & 3); }

    const u16* A = isQ ? queries_b : inputs_b;
    const u16* W = w_in_b + (isQ ? 0 : (size_t)E_DIM * E_DIM);
    const float* bias = b_in + (isQ ? 0 : E_DIM);
    const int m_blk = by * 128;
    const int n_blk = bx * 128;
    const int K = E_DIM;

    const int tid = threadIdx.x;
    const int l = tid & 63;
    const int w = tid >> 6;
    const int m0 = (w & 1) * 64;
    const int n0 = (w >> 1) * 64;
    const int quad = l >> 4;
    const int c = l & 15;

    f32x4 acc[4][4];
    #pragma unroll
    for (int i = 0; i < 4; ++i)
        #pragma unroll
        for (int j = 0; j < 4; ++j)
            acc[i][j] = (f32x4){0.f, 0.f, 0.f, 0.f};

    const int srow = l >> 2;            // 0..15
    const int skoff = (l & 3) * 8;      // u16 col within a 32-col half
    const u16* Ag = A + (size_t)(m_blk + w * 32 + srow) * K + skoff;
    const u16* Wg = W + (size_t)(n_blk + w * 32 + srow) * K + skoff;

    for (int k0 = 0; k0 < K; k0 += 64) {
        __syncthreads();
        #pragma unroll
        for (int hf = 0; hf < 2; ++hf)
            #pragma unroll
            for (int t = 0; t < 2; ++t) {
                const size_t soff = (size_t)t * 16 * K + k0 + hf * 32;
                const size_t doff = (size_t)(w * 32 + t * 16) * 32;
                async16(Ag + soff, &As[hf][0] + doff);
                async16(Wg + soff, &Ws[hf][0] + doff);
            }
        __syncthreads();

        #pragma unroll
        for (int hf = 0; hf < 2; ++hf) {
            bf16x8 af[4], wf[4];
            #pragma unroll
            for (int t = 0; t < 4; ++t) {
                af[t] = *(const bf16x8*)&As[hf][(m0 + t * 16 + c) * 32 + quad * 8];
                wf[t] = *(const bf16x8*)&Ws[hf][(n0 + t * 16 + c) * 32 + quad * 8];
            }
            #pragma unroll
            for (int i = 0; i < 4; ++i)
                #pragma unroll
                for (int j = 0; j < 4; ++j)
                    acc[i][j] = __builtin_amdgcn_mfma_f32_16x16x32_bf16(
                        af[i], wf[j], acc[i][j], 0, 0, 0);
        }
    }

    #pragma unroll
    for (int jj = 0; jj < 4; ++jj) {
        int col = n_blk + n0 + jj * 16 + c;
        float bv = bias[col];
        if (isQ || col < 1024) {
            u16* dst = isQ ? Qf : Kf;
            int hh = col >> 6, d = col & 63;
            int dq = d >> 3, dj = d & 7;
            #pragma unroll
            for (int i = 0; i < 4; ++i) {
                int t = (m_blk + m0 + i * 16) >> 4;
                size_t base = ((size_t)(t * NH + hh)) * 1024
                            + (size_t)(dq * 16 + quad * 4) * 8 + dj;
                #pragma unroll
                for (int r = 0; r < 4; ++r)
                    dst[base + (size_t)r * 8] = f2bf(acc[i][jj][r] + bv);
            }
        } else {
            int vcol = col - 1024;
            int hv = vcol >> 6, d = vcol & 63;
            int td = d >> 4, ct = d & 15;
            #pragma unroll
            for (int i = 0; i < 4; ++i) {
                int tok = m_blk + m0 + i * 16;
                int g32 = tok >> 5;
                int jo = (tok & 16) >> 2;          // 0 or 4
                ushort4 pk;
                pk.x = f2bf(acc[i][jj][0] + bv);
                pk.y = f2bf(acc[i][jj][1] + bv);
                pk.z = f2bf(acc[i][jj][2] + bv);
                pk.w = f2bf(acc[i][jj][3] + bv);
                *(ushort4*)(Vf + ((size_t)(g32 * NH + hv)) * 2048
                            + (size_t)((td * 4 + quad) * 16 + ct) * 8 + jo) = pk;
            }
        }
    }
}

// ---------------------------------------------------------------------------
// Attention.  (verbatim round-6: split pipeline qk(t+1) before smpv(t),
// defer-max, deferred l-reduction, cvt_pk pack, setprio around MFMA)
// ---------------------------------------------------------------------------
struct Kfrags { bf16x8 kf[4][2]; };
struct Vfrags { bf16x8 vf[2][4]; };

__global__ __launch_bounds__(256) void attn_kernel(
    const u16* __restrict__ Qf, const u16* __restrict__ Kf,
    const u16* __restrict__ Vf, u16* __restrict__ Ob)
{
    const int tid = threadIdx.x;
    const int l = tid & 63;
    const int w = tid >> 6;
    const int quad = l >> 4;
    const int c = l & 15;
    const int bid = blockIdx.x;
    const int h = bid & 15;
    const int b = (bid >> 4) & 7;
    const int qt = bid >> 7;
    const int q0 = b * LQ + qt * 64 + w * 16;
    const float C1 = 0.18033688011112042f;   // (1/8)*log2(e)
    const float THR = 8.0f;                  // defer-max threshold

    bf16x8 qf[2];
    {
        size_t qb = ((size_t)((q0 >> 4) * NH + h)) * 1024 + (size_t)l * 8;
        qf[0] = *(const bf16x8*)(Qf + qb);
        qf[1] = *(const bf16x8*)(Qf + qb + 512);
    }

    f32x4 o[4];
    #pragma unroll
    for (int td = 0; td < 4; ++td) o[td] = (f32x4){0.f, 0.f, 0.f, 0.f};
    float m_i = -1e30f;
    float lpart = 0.f;

    auto load_k = [&](int kv0, Kfrags& dst) {
        const int kvg = b * LKV + kv0;
        #pragma unroll
        for (int nt = 0; nt < 4; ++nt) {
            size_t kb = ((size_t)((((kvg >> 4) + nt) * NH) + h)) * 1024 + (size_t)l * 8;
            dst.kf[nt][0] = *(const bf16x8*)(Kf + kb);
            dst.kf[nt][1] = *(const bf16x8*)(Kf + kb + 512);
        }
    };
    auto load_v = [&](int kv0, Vfrags& dst) {
        const int kvg = b * LKV + kv0;
        #pragma unroll
        for (int g = 0; g < 2; ++g) {
            size_t vb = ((size_t)((((kvg >> 5) + g) * NH) + h)) * 2048 + (size_t)l * 8;
            #pragma unroll
            for (int td = 0; td < 4; ++td)
                dst.vf[g][td] = *(const bf16x8*)(Vf + vb + td * 512);
        }
    };

    auto qk = [&](Kfrags& ck, f32x4* s) {
        #pragma unroll
        for (int nt = 0; nt < 4; ++nt) s[nt] = (f32x4){0.f, 0.f, 0.f, 0.f};
        __builtin_amdgcn_s_setprio(1);
        #pragma unroll
        for (int nt = 0; nt < 4; ++nt)
            #pragma unroll
            for (int hk = 0; hk < 2; ++hk)
                s[nt] = __builtin_amdgcn_mfma_f32_16x16x32_bf16(
                    ck.kf[nt][hk], qf[hk], s[nt], 0, 0, 0);
        __builtin_amdgcn_s_setprio(0);
    };

    auto smpv = [&](f32x4* s, Vfrags& cv) {
        float m01 = fmaxf(fmaxf(s[0][0], s[0][1]), fmaxf(s[0][2], s[0][3]));
        float m23 = fmaxf(fmaxf(s[1][0], s[1][1]), fmaxf(s[1][2], s[1][3]));
        float m45 = fmaxf(fmaxf(s[2][0], s[2][1]), fmaxf(s[2][2], s[2][3]));
        float m67 = fmaxf(fmaxf(s[3][0], s[3][1]), fmaxf(s[3][2], s[3][3]));
        float vml = fmaxf(fmaxf(m01, m23), fmaxf(m45, m67));

        if (!__all(vml - m_i <= THR)) {
            float vmr = vml;
            vmr = fmaxf(vmr, __shfl_xor(vmr, 16, 64));
            vmr = fmaxf(vmr, __shfl_xor(vmr, 32, 64));
            float mnew = fmaxf(m_i, vmr);
            float alpha = __builtin_amdgcn_exp2f((m_i - mnew) * C1);
            m_i = mnew;
            lpart *= alpha;
            float ar[4];
            #pragma unroll
            for (int r = 0; r < 4; ++r) ar[r] = __shfl(alpha, quad * 4 + r, 16);
            #pragma unroll
            for (int td = 0; td < 4; ++td)
                #pragma unroll
                for (int r = 0; r < 4; ++r) o[td][r] *= ar[r];
        }

        float p[4][4];
        float rs = 0.f;
        #pragma unroll
        for (int nt = 0; nt < 4; ++nt)
            #pragma unroll
            for (int r = 0; r < 4; ++r) {
                p[nt][r] = __builtin_amdgcn_exp2f((s[nt][r] - m_i) * C1);
                rs += p[nt][r];
            }
        lpart += rs;

        bf16x8 af[2];
        #pragma unroll
        for (int g = 0; g < 2; ++g) {
            union { unsigned u[4]; bf16x8 v; } r_;
            r_.u[0] = pk2(p[2 * g][0],     p[2 * g][1]);
            r_.u[1] = pk2(p[2 * g][2],     p[2 * g][3]);
            r_.u[2] = pk2(p[2 * g + 1][0], p[2 * g + 1][1]);
            r_.u[3] = pk2(p[2 * g + 1][2], p[2 * g + 1][3]);
            af[g] = r_.v;
        }

        __builtin_amdgcn_s_setprio(1);
        #pragma unroll
        for (int g = 0; g < 2; ++g)
            #pragma unroll
            for (int td = 0; td < 4; ++td)
                o[td] = __builtin_amdgcn_mfma_f32_16x16x32_bf16(
                    af[g], cv.vf[g][td], o[td], 0, 0, 0);
        __builtin_amdgcn_s_setprio(0);
    };

    Kfrags K0, K1;
    Vfrags V0, V1;
    f32x4 s0[4], s1[4];
    load_k(0, K0);
    load_v(0, V0);
    load_k(64, K1);
    qk(K0, s0);
    #pragma unroll
    for (int it = 0; it < 16; it += 2) {
        if (it + 2 < 16) load_k((it + 2) * 64, K0);
        load_v((it + 1) * 64, V1);
        qk(K1, s1);
        smpv(s0, V0);
        if (it + 3 < 16) load_k((it + 3) * 64, K1);
        if (it + 2 < 16) { load_v((it + 2) * 64, V0); qk(K0, s0); }
        smpv(s1, V1);
    }

    float l_i = lpart;
    l_i += __shfl_xor(l_i, 16, 64);
    l_i += __shfl_xor(l_i, 32, 64);
    float invl = 1.f / l_i;
    float ir[4];
    #pragma unroll
    for (int r = 0; r < 4; ++r) ir[r] = __shfl(invl, quad * 4 + r, 16);
    #pragma unroll
    for (int td = 0; td < 4; ++td)
        #pragma unroll
        for (int r = 0; r < 4; ++r)
            Ob[(size_t)(q0 + quad * 4 + r) * E_DIM + h * 64 + td * 16 + c] =
                f2bf(o[td][r] * ir[r]);
}

// ---------------------------------------------------------------------------
// Output projection: out[4096,1024] = Ob @ w_out^T + b_out (fp32 out).
// 64x64 tiles, grid 1024 (4 blocks/CU = 16 waves/CU vs 128-tile's 4).
// Carried from round 7 (its effect was masked by the proj spill); this
// round cleanly A/Bs it against the 223.3 µs round-6 build.
// ---------------------------------------------------------------------------
__global__ __launch_bounds__(256) void out_gemm_kernel(
    const u16* __restrict__ A, const u16* __restrict__ W,
    const float* __restrict__ bias, float* __restrict__ Cf)
{
    __shared__ u16 As[2][64 * 32];
    __shared__ u16 Ws[2][64 * 32];

    const int K = E_DIM, N = E_DIM;
    const int bid = blockIdx.x;
    const int x = bid & 7;
    const int i_ = bid >> 3;            // 0..127
    const int m_blk = (x * 8 + (i_ & 7)) * 64;   // 64 m-blocks
    const int n_blk = (i_ >> 3) * 64;            // 16 n-blocks

    const int tid = threadIdx.x;
    const int l = tid & 63;
    const int w = tid >> 6;
    const int m0 = (w & 1) * 32;
    const int n0 = (w >> 1) * 32;
    const int quad = l >> 4;
    const int c = l & 15;

    f32x4 acc[2][2];
    #pragma unroll
    for (int i = 0; i < 2; ++i)
        #pragma unroll
        for (int j = 0; j < 2; ++j)
            acc[i][j] = (f32x4){0.f, 0.f, 0.f, 0.f};

    const int srow = l >> 2;            // 0..15
    const int skoff = (l & 3) * 8;
    const u16* Ag = A + (size_t)(m_blk + w * 16 + srow) * K + skoff;
    const u16* Wg = W + (size_t)(n_blk + w * 16 + srow) * K + skoff;

    for (int k0 = 0; k0 < K; k0 += 64) {
        __syncthreads();
        #pragma unroll
        for (int hf = 0; hf < 2; ++hf) {
            const size_t soff = (size_t)(k0 + hf * 32);
            const size_t doff = (size_t)(w * 16) * 32;
            async16(Ag + soff, &As[hf][0] + doff);
            async16(Wg + soff, &Ws[hf][0] + doff);
        }
        __syncthreads();

        #pragma unroll
        for (int hf = 0; hf < 2; ++hf) {
            bf16x8 af[2], wf[2];
            #pragma unroll
            for (int t = 0; t < 2; ++t) {
                af[t] = *(const bf16x8*)&As[hf][(m0 + t * 16 + c) * 32 + quad * 8];
                wf[t] = *(const bf16x8*)&Ws[hf][(n0 + t * 16 + c) * 32 + quad * 8];
            }
            #pragma unroll
            for (int i = 0; i < 2; ++i)
                #pragma unroll
                for (int j = 0; j < 2; ++j)
                    acc[i][j] = __builtin_amdgcn_mfma_f32_16x16x32_bf16(
                        wf[j], af[i], acc[i][j], 0, 0, 0);
        }
    }

    #pragma unroll
    for (int j = 0; j < 2; ++j) {
        const int colb = n_blk + n0 + j * 16 + quad * 4;
        const float4 bv = *(const float4*)&bias[colb];
        #pragma unroll
        for (int i = 0; i < 2; ++i) {
            const int row = m_blk + m0 + i * 16 + c;
            float4 o4;
            o4.x = acc[i][j][0] + bv.x;
            o4.y = acc[i][j][1] + bv.y;
            o4.z = acc[i][j][2] + bv.z;
            o4.w = acc[i][j][3] + bv.w;
            *(float4*)&Cf[(size_t)row * N + colb] = o4;
        }
    }
}

// ---------------------------------------------------------------------------
extern "C" void kernel_launch(void* const* d_in, const int* in_sizes, int n_in,
                              void* d_out, int out_size, void* d_ws, size_t ws_size,
                              hipStream_t stream) {
    const float* inputs  = (const float*)d_in[0];   // [8192,1024]
    const float* queries = (const float*)d_in[1];   // [4096,1024]
    const float* w_in    = (const float*)d_in[2];   // [3072,1024]
    const float* b_in    = (const float*)d_in[3];   // [3072]
    const float* w_out   = (const float*)d_in[4];   // [1024,1024]
    const float* b_out   = (const float*)d_in[5];   // [1024]
    float* out = (float*)d_out;                     // [4096,1024] fp32

    const int NQ = BSEG * LQ;    // 4096
    const int NKV = BSEG * LKV;  // 8192

    // workspace: 80 MB
    u16* inputs_b  = (u16*)d_ws;                                   // 16 MB
    u16* queries_b = inputs_b  + (size_t)NKV * E_DIM;              //  8 MB
    u16* w_in_b    = queries_b + (size_t)NQ * E_DIM;               //  6 MB
    u16* w_out_b   = w_in_b    + (size_t)3 * E_DIM * E_DIM;        //  2 MB
    u16* Qf        = w_out_b   + (size_t)E_DIM * E_DIM;            //  8 MB
    u16* Kf        = Qf        + (size_t)NQ * E_DIM;               // 16 MB
    u16* Vf        = Kf        + (size_t)NKV * E_DIM;              // 16 MB
    u16* Ob        = Vf        + (size_t)NKV * E_DIM;              //  8 MB

    dim3 blk(256);

    cvt_all_kernel<<<16384, blk, 0, stream>>>(
        inputs, queries, w_in, w_out, inputs_b, queries_b, w_in_b, w_out_b);

    proj_gemm_kernel<<<1280, blk, 0, stream>>>(
        inputs_b, queries_b, w_in_b, b_in, Kf, Qf, Vf);

    attn_kernel<<<1024, blk, 0, stream>>>(Qf, Kf, Vf, Ob);

    out_gemm_kernel<<<1024, blk, 0, stream>>>(
        Ob, w_out_b, b_out, out);
}

// Round 9
// 215.105 us; speedup vs baseline: 3.0467x; 1.0380x over previous
//
#include <hip/hip_runtime.h>

#define E_DIM 1024
#define NH 16
#define DH 64
#define BSEG 8
#define LQ 512
#define LKV 1024

typedef short bf16x8 __attribute__((ext_vector_type(8)));
typedef float f32x4 __attribute__((ext_vector_type(4)));
typedef unsigned short u16;

// round-to-nearest-even fp32 -> bf16 bits
__device__ __forceinline__ u16 f2bf(float x) {
    unsigned u = __float_as_uint(x);
    u += 0x7FFF + ((u >> 16) & 1);
    return (u16)(u >> 16);
}

// async global->LDS, 16B per lane; lds dest wave-uniform base + lane*16
__device__ __forceinline__ void async16(const void* g, const void* l) {
    __builtin_amdgcn_global_load_lds(
        (const __attribute__((address_space(1))) unsigned int*)g,
        (__attribute__((address_space(3))) unsigned int*)l, 16, 0, 0);
}

// packed RNE f32->bf16 pair -> one u32 (v_cvt_pk_bf16_f32)
__device__ __forceinline__ unsigned pk2(float a, float b) {
    unsigned r;
    asm("v_cvt_pk_bf16_f32 %0, %1, %2" : "=v"(r) : "v"(a), "v"(b));
    return r;
}

// ---------------------------------------------------------------------------
// Fused fp32->bf16 convert for all 4 inputs (one launch).  (verbatim)
// ---------------------------------------------------------------------------
__global__ __launch_bounds__(256) void cvt_all_kernel(
    const float* __restrict__ inputs, const float* __restrict__ queries,
    const float* __restrict__ w_in, const float* __restrict__ w_out,
    u16* __restrict__ ib, u16* __restrict__ qb,
    u16* __restrict__ wib, u16* __restrict__ wob)
{
    int blk = blockIdx.x;
    const float* s; u16* d; int base;
    if (blk < 8192)        { s = inputs;  d = ib;  base = blk; }
    else if (blk < 12288)  { s = queries; d = qb;  base = blk - 8192; }
    else if (blk < 15360)  { s = w_in;    d = wib; base = blk - 12288; }
    else                   { s = w_out;   d = wob; base = blk - 15360; }
    int i = base * 256 + threadIdx.x;
    float4 v = ((const float4*)s)[i];
    ushort4 o;
    o.x = f2bf(v.x); o.y = f2bf(v.y); o.z = f2bf(v.z); o.w = f2bf(v.w);
    ((ushort4*)d)[i] = o;
}

// ---------------------------------------------------------------------------
// Fused Q/K/V projection GEMM.  (verbatim round-8 / round-6: 60-62 µs,
// VGPR 48, no spill.  Do NOT add the swapped epilogue under the (256,5)
// cap — it spills accumulators to scratch, round-7 lesson.)
// ---------------------------------------------------------------------------
__global__ __launch_bounds__(256, 5) void proj_gemm_kernel(
    const u16* __restrict__ inputs_b, const u16* __restrict__ queries_b,
    const u16* __restrict__ w_in_b, const float* __restrict__ b_in,
    u16* __restrict__ Kf, u16* __restrict__ Qf, u16* __restrict__ Vf)
{
    __shared__ u16 As[2][128 * 32];
    __shared__ u16 Ws[2][128 * 32];

    const int bid = blockIdx.x;
    const bool isQ = (bid >= 1024);
    const int x = bid & 7;
    int bx, by;
    if (!isQ) { int i = bid >> 3;          bx = i >> 3; by = x * 8 + (i & 7); }
    else      { int i = (bid - 1024) >> 3; bx = i >> 2; by = x * 4 + (i & 3); }

    const u16* A = isQ ? queries_b : inputs_b;
    const u16* W = w_in_b + (isQ ? 0 : (size_t)E_DIM * E_DIM);
    const float* bias = b_in + (isQ ? 0 : E_DIM);
    const int m_blk = by * 128;
    const int n_blk = bx * 128;
    const int K = E_DIM;

    const int tid = threadIdx.x;
    const int l = tid & 63;
    const int w = tid >> 6;
    const int m0 = (w & 1) * 64;
    const int n0 = (w >> 1) * 64;
    const int quad = l >> 4;
    const int c = l & 15;

    f32x4 acc[4][4];
    #pragma unroll
    for (int i = 0; i < 4; ++i)
        #pragma unroll
        for (int j = 0; j < 4; ++j)
            acc[i][j] = (f32x4){0.f, 0.f, 0.f, 0.f};

    const int srow = l >> 2;            // 0..15
    const int skoff = (l & 3) * 8;      // u16 col within a 32-col half
    const u16* Ag = A + (size_t)(m_blk + w * 32 + srow) * K + skoff;
    const u16* Wg = W + (size_t)(n_blk + w * 32 + srow) * K + skoff;

    for (int k0 = 0; k0 < K; k0 += 64) {
        __syncthreads();
        #pragma unroll
        for (int hf = 0; hf < 2; ++hf)
            #pragma unroll
            for (int t = 0; t < 2; ++t) {
                const size_t soff = (size_t)t * 16 * K + k0 + hf * 32;
                const size_t doff = (size_t)(w * 32 + t * 16) * 32;
                async16(Ag + soff, &As[hf][0] + doff);
                async16(Wg + soff, &Ws[hf][0] + doff);
            }
        __syncthreads();

        #pragma unroll
        for (int hf = 0; hf < 2; ++hf) {
            bf16x8 af[4], wf[4];
            #pragma unroll
            for (int t = 0; t < 4; ++t) {
                af[t] = *(const bf16x8*)&As[hf][(m0 + t * 16 + c) * 32 + quad * 8];
                wf[t] = *(const bf16x8*)&Ws[hf][(n0 + t * 16 + c) * 32 + quad * 8];
            }
            #pragma unroll
            for (int i = 0; i < 4; ++i)
                #pragma unroll
                for (int j = 0; j < 4; ++j)
                    acc[i][j] = __builtin_amdgcn_mfma_f32_16x16x32_bf16(
                        af[i], wf[j], acc[i][j], 0, 0, 0);
        }
    }

    #pragma unroll
    for (int jj = 0; jj < 4; ++jj) {
        int col = n_blk + n0 + jj * 16 + c;
        float bv = bias[col];
        if (isQ || col < 1024) {
            u16* dst = isQ ? Qf : Kf;
            int hh = col >> 6, d = col & 63;
            int dq = d >> 3, dj = d & 7;
            #pragma unroll
            for (int i = 0; i < 4; ++i) {
                int t = (m_blk + m0 + i * 16) >> 4;
                size_t base = ((size_t)(t * NH + hh)) * 1024
                            + (size_t)(dq * 16 + quad * 4) * 8 + dj;
                #pragma unroll
                for (int r = 0; r < 4; ++r)
                    dst[base + (size_t)r * 8] = f2bf(acc[i][jj][r] + bv);
            }
        } else {
            int vcol = col - 1024;
            int hv = vcol >> 6, d = vcol & 63;
            int td = d >> 4, ct = d & 15;
            #pragma unroll
            for (int i = 0; i < 4; ++i) {
                int tok = m_blk + m0 + i * 16;
                int g32 = tok >> 5;
                int jo = (tok & 16) >> 2;          // 0 or 4
                ushort4 pk;
                pk.x = f2bf(acc[i][jj][0] + bv);
                pk.y = f2bf(acc[i][jj][1] + bv);
                pk.z = f2bf(acc[i][jj][2] + bv);
                pk.w = f2bf(acc[i][jj][3] + bv);
                *(ushort4*)(Vf + ((size_t)(g32 * NH + hv)) * 2048
                            + (size_t)((td * 4 + quad) * 16 + ct) * 8 + jo) = pk;
            }
        }
    }
}

// ---------------------------------------------------------------------------
// Attention.  Round-9: block-level LDS staging of K/V.
// Previously all 4 waves issued IDENTICAL global loads (kb/vb independent
// of w) — 4x redundant VMEM, 256 loads/wave, ~104 VGPR of register dbuf.
// Now: the block stages the 16 KB K+V tile ONCE via async16 (Kf/Vf are
// already fragment-ordered in global memory, so the LDS tile is a verbatim
// byte-copy: linear dest, no swizzle needed), double-buffered, T3-minimum
// schedule (stage(next) BEFORE compute(cur), ONE barrier per step whose
// vmcnt(0) drain waits on loads that had a full compute phase to land).
// Fragment reads become lane-linear ds_read_b128 (conflict-free).
// Softmax path (defer-max, deferred-l, cvt_pk pack) unchanged — numerics
// bit-identical to rounds 5-8.
// ---------------------------------------------------------------------------
__global__ __launch_bounds__(256) void attn_kernel(
    const u16* __restrict__ Qf, const u16* __restrict__ Kf,
    const u16* __restrict__ Vf, u16* __restrict__ Ob)
{
    __shared__ u16 Ks[2][4096];
    __shared__ u16 Vs[2][4096];

    const int tid = threadIdx.x;
    const int l = tid & 63;
    const int w = tid >> 6;
    const int quad = l >> 4;
    const int c = l & 15;
    const int bid = blockIdx.x;
    const int h = bid & 15;
    const int b = (bid >> 4) & 7;
    const int qt = bid >> 7;
    const int q0 = b * LQ + qt * 64 + w * 16;
    const float C1 = 0.18033688011112042f;   // (1/8)*log2(e)
    const float THR = 8.0f;                  // defer-max threshold

    bf16x8 qf[2];
    {
        size_t qb = ((size_t)((q0 >> 4) * NH + h)) * 1024 + (size_t)l * 8;
        qf[0] = *(const bf16x8*)(Qf + qb);
        qf[1] = *(const bf16x8*)(Qf + qb + 512);
    }

    f32x4 o[4];
    #pragma unroll
    for (int td = 0; td < 4; ++td) o[td] = (f32x4){0.f, 0.f, 0.f, 0.f};
    float m_i = -1e30f;
    float lpart = 0.f;

    // Stage the 64-kv tile starting at kv0 into buffer `buf`.
    // K: 4 chunks of 1024 u16 (frag16), concatenated -> Ks[buf][nt*1024+..]
    // V: 2 chunks of 2048 u16 (sigma'),  concatenated -> Vs[buf][g*2048+..]
    // Per round r (2 rounds): wave w stages 1 KB of K and 1 KB of V.
    auto stage = [&](int buf, int kv0) {
        const int kvg = b * LKV + kv0;
        const int t16 = kvg >> 4;
        const int t32 = kvg >> 5;
        #pragma unroll
        for (int r = 0; r < 2; ++r) {
            const int nt = 2 * r + (w >> 1);
            const u16* ksrc = Kf + ((size_t)((t16 + nt) * NH + h)) * 1024
                            + (w & 1) * 512 + l * 8;
            async16(ksrc, &Ks[buf][r * 2048 + w * 512 + l * 8]);
            const u16* vsrc = Vf + ((size_t)((t32 + r) * NH + h)) * 2048
                            + w * 512 + l * 8;
            async16(vsrc, &Vs[buf][r * 2048 + w * 512 + l * 8]);
        }
    };

    auto step_lds = [&](int buf) {
        // S^T = K · Q^T from LDS K frags
        f32x4 s[4];
        #pragma unroll
        for (int nt = 0; nt < 4; ++nt) s[nt] = (f32x4){0.f, 0.f, 0.f, 0.f};
        __builtin_amdgcn_s_setprio(1);
        #pragma unroll
        for (int nt = 0; nt < 4; ++nt)
            #pragma unroll
            for (int hk = 0; hk < 2; ++hk) {
                bf16x8 kf = *(const bf16x8*)&Ks[buf][nt * 1024 + hk * 512 + l * 8];
                s[nt] = __builtin_amdgcn_mfma_f32_16x16x32_bf16(
                    kf, qf[hk], s[nt], 0, 0, 0);
            }
        __builtin_amdgcn_s_setprio(0);

        // softmax (defer-max), verbatim
        float m01 = fmaxf(fmaxf(s[0][0], s[0][1]), fmaxf(s[0][2], s[0][3]));
        float m23 = fmaxf(fmaxf(s[1][0], s[1][1]), fmaxf(s[1][2], s[1][3]));
        float m45 = fmaxf(fmaxf(s[2][0], s[2][1]), fmaxf(s[2][2], s[2][3]));
        float m67 = fmaxf(fmaxf(s[3][0], s[3][1]), fmaxf(s[3][2], s[3][3]));
        float vml = fmaxf(fmaxf(m01, m23), fmaxf(m45, m67));

        if (!__all(vml - m_i <= THR)) {
            float vmr = vml;
            vmr = fmaxf(vmr, __shfl_xor(vmr, 16, 64));
            vmr = fmaxf(vmr, __shfl_xor(vmr, 32, 64));
            float mnew = fmaxf(m_i, vmr);
            float alpha = __builtin_amdgcn_exp2f((m_i - mnew) * C1);
            m_i = mnew;
            lpart *= alpha;
            float ar[4];
            #pragma unroll
            for (int r = 0; r < 4; ++r) ar[r] = __shfl(alpha, quad * 4 + r, 16);
            #pragma unroll
            for (int td = 0; td < 4; ++td)
                #pragma unroll
                for (int r = 0; r < 4; ++r) o[td][r] *= ar[r];
        }

        float p[4][4];
        float rs = 0.f;
        #pragma unroll
        for (int nt = 0; nt < 4; ++nt)
            #pragma unroll
            for (int r = 0; r < 4; ++r) {
                p[nt][r] = __builtin_amdgcn_exp2f((s[nt][r] - m_i) * C1);
                rs += p[nt][r];
            }
        lpart += rs;

        bf16x8 af[2];
        #pragma unroll
        for (int g = 0; g < 2; ++g) {
            union { unsigned u[4]; bf16x8 v; } r_;
            r_.u[0] = pk2(p[2 * g][0],     p[2 * g][1]);
            r_.u[1] = pk2(p[2 * g][2],     p[2 * g][3]);
            r_.u[2] = pk2(p[2 * g + 1][0], p[2 * g + 1][1]);
            r_.u[3] = pk2(p[2 * g + 1][2], p[2 * g + 1][3]);
            af[g] = r_.v;
        }

        // PV from LDS V frags
        __builtin_amdgcn_s_setprio(1);
        #pragma unroll
        for (int g = 0; g < 2; ++g)
            #pragma unroll
            for (int td = 0; td < 4; ++td) {
                bf16x8 vf = *(const bf16x8*)&Vs[buf][g * 2048 + td * 512 + l * 8];
                o[td] = __builtin_amdgcn_mfma_f32_16x16x32_bf16(
                    af[g], vf, o[td], 0, 0, 0);
            }
        __builtin_amdgcn_s_setprio(0);
    };

    // T3-minimum 2-phase: stage(next) issued before compute(cur);
    // one barrier per step drains the prefetch (vmcnt0) + protects buffers.
    stage(0, 0);
    __syncthreads();
    int cur = 0;
    #pragma unroll 2
    for (int it = 0; it < 16; ++it) {
        if (it < 15) stage(cur ^ 1, (it + 1) * 64);
        step_lds(cur);
        __syncthreads();
        cur ^= 1;
    }

    // epilogue: finish deferred l reduction, normalize
    float l_i = lpart;
    l_i += __shfl_xor(l_i, 16, 64);
    l_i += __shfl_xor(l_i, 32, 64);
    float invl = 1.f / l_i;
    float ir[4];
    #pragma unroll
    for (int r = 0; r < 4; ++r) ir[r] = __shfl(invl, quad * 4 + r, 16);
    #pragma unroll
    for (int td = 0; td < 4; ++td)
        #pragma unroll
        for (int r = 0; r < 4; ++r)
            Ob[(size_t)(q0 + quad * 4 + r) * E_DIM + h * 64 + td * 16 + c] =
                f2bf(o[td][r] * ir[r]);
}

// ---------------------------------------------------------------------------
// Output projection: out[4096,1024] = Ob @ w_out^T + b_out (fp32 out).
// (verbatim round-8: 64x64 tiles, grid 1024, swapped operands/float4 stores)
// ---------------------------------------------------------------------------
__global__ __launch_bounds__(256) void out_gemm_kernel(
    const u16* __restrict__ A, const u16* __restrict__ W,
    const float* __restrict__ bias, float* __restrict__ Cf)
{
    __shared__ u16 As[2][64 * 32];
    __shared__ u16 Ws[2][64 * 32];

    const int K = E_DIM, N = E_DIM;
    const int bid = blockIdx.x;
    const int x = bid & 7;
    const int i_ = bid >> 3;            // 0..127
    const int m_blk = (x * 8 + (i_ & 7)) * 64;   // 64 m-blocks
    const int n_blk = (i_ >> 3) * 64;            // 16 n-blocks

    const int tid = threadIdx.x;
    const int l = tid & 63;
    const int w = tid >> 6;
    const int m0 = (w & 1) * 32;
    const int n0 = (w >> 1) * 32;
    const int quad = l >> 4;
    const int c = l & 15;

    f32x4 acc[2][2];
    #pragma unroll
    for (int i = 0; i < 2; ++i)
        #pragma unroll
        for (int j = 0; j < 2; ++j)
            acc[i][j] = (f32x4){0.f, 0.f, 0.f, 0.f};

    const int srow = l >> 2;            // 0..15
    const int skoff = (l & 3) * 8;
    const u16* Ag = A + (size_t)(m_blk + w * 16 + srow) * K + skoff;
    const u16* Wg = W + (size_t)(n_blk + w * 16 + srow) * K + skoff;

    for (int k0 = 0; k0 < K; k0 += 64) {
        __syncthreads();
        #pragma unroll
        for (int hf = 0; hf < 2; ++hf) {
            const size_t soff = (size_t)(k0 + hf * 32);
            const size_t doff = (size_t)(w * 16) * 32;
            async16(Ag + soff, &As[hf][0] + doff);
            async16(Wg + soff, &Ws[hf][0] + doff);
        }
        __syncthreads();

        #pragma unroll
        for (int hf = 0; hf < 2; ++hf) {
            bf16x8 af[2], wf[2];
            #pragma unroll
            for (int t = 0; t < 2; ++t) {
                af[t] = *(const bf16x8*)&As[hf][(m0 + t * 16 + c) * 32 + quad * 8];
                wf[t] = *(const bf16x8*)&Ws[hf][(n0 + t * 16 + c) * 32 + quad * 8];
            }
            #pragma unroll
            for (int i = 0; i < 2; ++i)
                #pragma unroll
                for (int j = 0; j < 2; ++j)
                    acc[i][j] = __builtin_amdgcn_mfma_f32_16x16x32_bf16(
                        wf[j], af[i], acc[i][j], 0, 0, 0);
        }
    }

    #pragma unroll
    for (int j = 0; j < 2; ++j) {
        const int colb = n_blk + n0 + j * 16 + quad * 4;
        const float4 bv = *(const float4*)&bias[colb];
        #pragma unroll
        for (int i = 0; i < 2; ++i) {
            const int row = m_blk + m0 + i * 16 + c;
            float4 o4;
            o4.x = acc[i][j][0] + bv.x;
            o4.y = acc[i][j][1] + bv.y;
            o4.z = acc[i][j][2] + bv.z;
            o4.w = acc[i][j][3] + bv.w;
            *(float4*)&Cf[(size_t)row * N + colb] = o4;
        }
    }
}

// ---------------------------------------------------------------------------
extern "C" void kernel_launch(void* const* d_in, const int* in_sizes, int n_in,
                              void* d_out, int out_size, void* d_ws, size_t ws_size,
                              hipStream_t stream) {
    const float* inputs  = (const float*)d_in[0];   // [8192,1024]
    const float* queries = (const float*)d_in[1];   // [4096,1024]
    const float* w_in    = (const float*)d_in[2];   // [3072,1024]
    const float* b_in    = (const float*)d_in[3];   // [3072]
    const float* w_out   = (const float*)d_in[4];   // [1024,1024]
    const float* b_out   = (const float*)d_in[5];   // [1024]
    float* out = (float*)d_out;                     // [4096,1024] fp32

    const int NQ = BSEG * LQ;    // 4096
    const int NKV = BSEG * LKV;  // 8192

    // workspace: 80 MB
    u16* inputs_b  = (u16*)d_ws;                                   // 16 MB
    u16* queries_b = inputs_b  + (size_t)NKV * E_DIM;              //  8 MB
    u16* w_in_b    = queries_b + (size_t)NQ * E_DIM;               //  6 MB
    u16* w_out_b   = w_in_b    + (size_t)3 * E_DIM * E_DIM;        //  2 MB
    u16* Qf        = w_out_b   + (size_t)E_DIM * E_DIM;            //  8 MB
    u16* Kf        = Qf        + (size_t)NQ * E_DIM;               // 16 MB
    u16* Vf        = Kf        + (size_t)NKV * E_DIM;              // 16 MB
    u16* Ob        = Vf        + (size_t)NKV * E_DIM;              //  8 MB

    dim3 blk(256);

    cvt_all_kernel<<<16384, blk, 0, stream>>>(
        inputs, queries, w_in, w_out, inputs_b, queries_b, w_in_b, w_out_b);

    proj_gemm_kernel<<<1280, blk, 0, stream>>>(
        inputs_b, queries_b, w_in_b, b_in, Kf, Qf, Vf);

    attn_kernel<<<1024, blk, 0, stream>>>(Qf, Kf, Vf, Ob);

    out_gemm_kernel<<<1024, blk, 0, stream>>>(
        Ob, w_out_b, b_out, out);
}